// Round 1
// baseline (14996.127 us; speedup 1.0000x reference)
//
#include <hip/hip_runtime.h>

typedef _Float16 f16;
typedef _Float16 f16x8 __attribute__((ext_vector_type(8)));
typedef float f32x4 __attribute__((ext_vector_type(4)));
typedef unsigned int u32;
typedef unsigned long long u64;

#define SEQ 2048
#define NB 64
#define NH 512
#define LDS_BYTES 133376          // 2*65536 (W slices) + 2304 (repack tile)
#define OUT0_ELEMS (SEQ * NB * NH)  // 67108864

#define AGENT __HIP_MEMORY_SCOPE_AGENT
#define RLX __ATOMIC_RELAXED

#define MFMA16(a, b, c) __builtin_amdgcn_mfma_f32_16x16x32_f16((a), (b), (c), 0, 0, 0)

__device__ __forceinline__ uint4 ld_sc(const void* p) {
  uint4 d;
  asm volatile("global_load_dwordx4 %0, %1, off sc0 sc1" : "=v"(d) : "v"(p) : "memory");
  return d;
}

#define WAIT_VM0()                                                \
  {                                                               \
    asm volatile("s_waitcnt vmcnt(0)" ::: "memory");              \
    __builtin_amdgcn_sched_barrier(0);                            \
  }

__device__ __forceinline__ f16x8 as_f16x8(uint4 v) {
  union { uint4 u; f16x8 h; } x;
  x.u = v;
  return x.h;
}

__device__ __forceinline__ f16x8 ldcvt8(const float* p) {
  float4 a = *(const float4*)p;
  float4 b = *(const float4*)(p + 4);
  f16x8 v;
  v[0] = (f16)a.x; v[1] = (f16)a.y; v[2] = (f16)a.z; v[3] = (f16)a.w;
  v[4] = (f16)b.x; v[5] = (f16)b.y; v[6] = (f16)b.z; v[7] = (f16)b.w;
  return v;
}

// Spin until all 8 flags >= tgt. All threads call; no barriers inside.
__device__ __forceinline__ bool spin8(u32* f8, u32 tgt, u32* gab) {
  int it = 0;
  for (;;) {
    u32 f = __hip_atomic_load(&f8[threadIdx.x & 7], RLX, AGENT);
    if (__all((int)(f >= tgt))) break;
    if (((++it) & 255) == 0) {
      u32 g = __hip_atomic_load(gab, RLX, AGENT);
      if (g || it > (1 << 22)) {
        __hip_atomic_store(gab, 1u, RLX, AGENT);
        return false;
      }
    }
    __builtin_amdgcn_s_sleep(1);
  }
  asm volatile("" ::: "memory");
  return true;
}

__device__ __forceinline__ bool spin1(u32* f, u32 tgt, u32* gab) {
  int it = 0;
  for (;;) {
    u32 v = __hip_atomic_load(f, RLX, AGENT);
    if (v >= tgt) break;
    if (((++it) & 255) == 0) {
      u32 g = __hip_atomic_load(gab, RLX, AGENT);
      if (g || it > (1 << 22)) {
        __hip_atomic_store(gab, 1u, RLX, AGENT);
        return false;
      }
    }
    __builtin_amdgcn_s_sleep(1);
  }
  asm volatile("" ::: "memory");
  return true;
}

// B-fragment from swizzled LDS W slice: lane needs W[jl][kk*32 + 8*kgrp .. +8]
#define BFRAG(Wb, kk) \
  (*(const f16x8*)((Wb) + jl * 1024 + ((((kk) * 64) + kgrp * 16) ^ swz)))

// grid = 64 WGs: cluster = bid>>4 (16 batches each), layer = (bid>>3)&1, r = bid&7 (64-row slice)
__global__ __launch_bounds__(256, 1) void rnn_fused(
    const float* __restrict__ x, const float* __restrict__ hx,
    const float* __restrict__ w_ih, const float* __restrict__ w_hh,
    const float* __restrict__ b_ih, const float* __restrict__ b_hh,
    float* __restrict__ out, char* __restrict__ ws) {
  extern __shared__ char smem[];
  char* Wi = smem;             // [64][512] f16, swizzled
  char* Wh = smem + 65536;     // [64][512] f16, swizzled
  char* RP = smem + 131072;    // repack tile [16 b][64 j] f16, row stride 144 B

  const int tid = threadIdx.x;
  const int lane = tid & 63;
  const int wv = tid >> 6;
  const int mrow = lane & 15;   // A/M row (batch) ; also D col index source
  const int kgrp = lane >> 4;   // 0..3
  const int jl = wv * 16 + mrow;       // output-feature row within 64-row slice
  const int swz = (jl & 7) << 4;
  const int aoff = mrow * 1024 + kgrp * 16;  // A-frag byte offset in a [16][512] f16 tile

  const int bid = blockIdx.x;
  const int cl = bid >> 4;
  const int layer = (bid >> 3) & 1;
  const int r = bid & 7;
  const int jg = r * 64 + jl;   // global feature index 0..511

  u32* flags0 = (u32*)(ws + cl * 64);
  u32* flags1 = (u32*)(ws + 256 + cl * 64);
  u32* prog = (u32*)(ws + 512 + cl * 64);
  u32* gab = (u32*)(ws + 768);
  char* ring0 = ws + 1024 + cl * 131072;            // [8][16][512] f16
  char* ring1 = ws + 1024 + 524288 + cl * 32768;    // [2][16][512] f16

  // ---- load W slices into LDS as f16, XOR-swizzled (G4) ----
#pragma unroll 1
  for (int m = 0; m < 2; ++m) {
    const float* src = (m ? w_hh : w_ih) + (size_t)layer * NH * NH + (size_t)(r * 64) * NH;
    char* dst = m ? Wh : Wi;
#pragma unroll 1
    for (int q = 0; q < 16; ++q) {
      int g = q * 256 + tid;
      int row = g >> 6;
      int k8 = (g & 63) * 8;
      f16x8 v = ldcvt8(src + row * NH + k8);
      *(f16x8*)(dst + row * 1024 + ((k8 * 2) ^ ((row & 7) << 4))) = v;
    }
  }
  const float bias = b_ih[layer * NH + jg] + b_hh[layer * NH + jg];
  __syncthreads();

  if (layer == 0) {
    // =================== LAYER 0 cluster ===================
    f32x4 acc;
    acc[0] = bias; acc[1] = bias; acc[2] = bias; acc[3] = bias;
    {  // prologue: acc = bias + w_ih0 @ x[0]
      const float* xb = x + (size_t)(cl * 16 + mrow) * NH + kgrp * 8;
#pragma unroll
      for (int kk = 0; kk < 16; ++kk)
        acc = MFMA16(ldcvt8(xb + kk * 32), BFRAG(Wi, kk), acc);
    }
    for (int t = 0; t < SEQ; ++t) {
      // --- recurrent GEMM: acc += w_hh0 @ h0[t-1] ---
      if (t == 0) {
        const float* hb = hx + (size_t)(cl * 16 + mrow) * NH + kgrp * 8;
#pragma unroll
        for (int kk = 0; kk < 16; ++kk)
          acc = MFMA16(ldcvt8(hb + kk * 32), BFRAG(Wh, kk), acc);
      } else {
        if (!spin8(flags0, (u32)t, gab)) return;
        if (t >= 8) {
          if (!spin1(prog, (u32)(t - 6), gab)) return;  // ring0 back-pressure
        }
        const char* hb = ring0 + ((t - 1) & 7) * 16384 + aoff;
        uint4 hf[16];
#pragma unroll
        for (int kk = 0; kk < 16; ++kk) hf[kk] = ld_sc(hb + kk * 64);
        WAIT_VM0();
#pragma unroll
        for (int kk = 0; kk < 16; ++kk)
          acc = MFMA16(as_f16x8(hf[kk]), BFRAG(Wh, kk), acc);
      }
      // --- relu ---
      float hv0 = fmaxf(acc[0], 0.f), hv1 = fmaxf(acc[1], 0.f);
      float hv2 = fmaxf(acc[2], 0.f), hv3 = fmaxf(acc[3], 0.f);
      if (t == SEQ - 1) {  // h_final layer 0
        float* hfo = out + OUT0_ELEMS + (size_t)(cl * 16) * NH;
        hfo[(size_t)(4 * kgrp + 0) * NH + jg] = hv0;
        hfo[(size_t)(4 * kgrp + 1) * NH + jg] = hv1;
        hfo[(size_t)(4 * kgrp + 2) * NH + jg] = hv2;
        hfo[(size_t)(4 * kgrp + 3) * NH + jg] = hv3;
      }
      // --- repack D-frags -> [b][j] tile in LDS ---
      *(f16*)(RP + (4 * kgrp + 0) * 144 + jl * 2) = (f16)hv0;
      *(f16*)(RP + (4 * kgrp + 1) * 144 + jl * 2) = (f16)hv1;
      *(f16*)(RP + (4 * kgrp + 2) * 144 + jl * 2) = (f16)hv2;
      *(f16*)(RP + (4 * kgrp + 3) * 144 + jl * 2) = (f16)hv3;
      __syncthreads();
      if (tid < 128) {  // slice -> ring0 slot t&7 (through L3)
        int bb = tid >> 3, seg = tid & 7;
        uint4 d = *(const uint4*)(RP + bb * 144 + seg * 16);
        u64* dst = (u64*)(ring0 + (t & 7) * 16384 + bb * 1024 + r * 128 + seg * 16);
        __hip_atomic_store(dst + 0, ((u64)d.y << 32) | d.x, RLX, AGENT);
        __hip_atomic_store(dst + 1, ((u64)d.w << 32) | d.z, RLX, AGENT);
      }
      WAIT_VM0();        // drain slice stores to coherence point
      __syncthreads();   // all waves' stores drained before flag
      if (tid == 0) __hip_atomic_store(&flags0[r], (u32)(t + 1), RLX, AGENT);
      // --- shadow: acc(t+1) = bias + w_ih0 @ x[t+1] ---
      if (t < SEQ - 1) {
        acc[0] = bias; acc[1] = bias; acc[2] = bias; acc[3] = bias;
        const float* xb = x + ((size_t)(t + 1) * NB + cl * 16 + mrow) * NH + kgrp * 8;
#pragma unroll
        for (int kk = 0; kk < 16; ++kk)
          acc = MFMA16(ldcvt8(xb + kk * 32), BFRAG(Wi, kk), acc);
      }
    }
  } else {
    // =================== LAYER 1 cluster ===================
    if (!spin8(flags0, 1u, gab)) return;
    uint4 h0f[16];
    {
      const char* hb = ring0 + aoff;  // slot 0 = h0[0]
#pragma unroll
      for (int kk = 0; kk < 16; ++kk) h0f[kk] = ld_sc(hb + kk * 64);
      WAIT_VM0();
    }
    f32x4 acc;
    acc[0] = bias; acc[1] = bias; acc[2] = bias; acc[3] = bias;
#pragma unroll
    for (int kk = 0; kk < 16; ++kk)
      acc = MFMA16(as_f16x8(h0f[kk]), BFRAG(Wi, kk), acc);

    for (int t = 0; t < SEQ; ++t) {
      // a': issue gather of h0[t+1] (parked; consumed in shadow phase)
      if (t < SEQ - 1) {
        if (!spin8(flags0, (u32)(t + 2), gab)) return;
        const char* hb = ring0 + ((t + 1) & 7) * 16384 + aoff;
#pragma unroll
        for (int kk = 0; kk < 16; ++kk) h0f[kk] = ld_sc(hb + kk * 64);
      }
      // b': acc += w_hh1 @ h1[t-1]
      if (t == 0) {
        const float* hb = hx + (size_t)(NB + cl * 16 + mrow) * NH + kgrp * 8;
#pragma unroll
        for (int kk = 0; kk < 16; ++kk)
          acc = MFMA16(ldcvt8(hb + kk * 32), BFRAG(Wh, kk), acc);
      } else {
        if (!spin8(flags1, (u32)t, gab)) return;
        const char* hb = ring1 + ((t - 1) & 1) * 16384 + aoff;
        uint4 h1f[16];
#pragma unroll
        for (int kk = 0; kk < 16; ++kk) h1f[kk] = ld_sc(hb + kk * 64);
        WAIT_VM0();
#pragma unroll
        for (int kk = 0; kk < 16; ++kk)
          acc = MFMA16(as_f16x8(h1f[kk]), BFRAG(Wh, kk), acc);
      }
      float hv0 = fmaxf(acc[0], 0.f), hv1 = fmaxf(acc[1], 0.f);
      float hv2 = fmaxf(acc[2], 0.f), hv3 = fmaxf(acc[3], 0.f);
      if (t == SEQ - 1) {  // h_final layer 1
        float* hfo = out + OUT0_ELEMS + (size_t)(NB + cl * 16) * NH;
        hfo[(size_t)(4 * kgrp + 0) * NH + jg] = hv0;
        hfo[(size_t)(4 * kgrp + 1) * NH + jg] = hv1;
        hfo[(size_t)(4 * kgrp + 2) * NH + jg] = hv2;
        hfo[(size_t)(4 * kgrp + 3) * NH + jg] = hv3;
      }
      *(f16*)(RP + (4 * kgrp + 0) * 144 + jl * 2) = (f16)hv0;
      *(f16*)(RP + (4 * kgrp + 1) * 144 + jl * 2) = (f16)hv1;
      *(f16*)(RP + (4 * kgrp + 2) * 144 + jl * 2) = (f16)hv2;
      *(f16*)(RP + (4 * kgrp + 3) * 144 + jl * 2) = (f16)hv3;
      __syncthreads();
      if (tid < 128) {
        int bb = tid >> 3, seg = tid & 7;
        uint4 d = *(const uint4*)(RP + bb * 144 + seg * 16);
        u64* dst = (u64*)(ring1 + (t & 1) * 16384 + bb * 1024 + r * 128 + seg * 16);
        __hip_atomic_store(dst + 0, ((u64)d.y << 32) | d.x, RLX, AGENT);
        __hip_atomic_store(dst + 1, ((u64)d.w << 32) | d.z, RLX, AGENT);
      }
      WAIT_VM0();
      __syncthreads();
      if (tid == 0) {
        __hip_atomic_store(&flags1[r], (u32)(t + 1), RLX, AGENT);
        if (r == 0) __hip_atomic_store(prog, (u32)(t + 1), RLX, AGENT);
      }
      {  // final output: out[t][b][j] fp32 (plain stores, fire-and-forget)
        float* ob = out + ((size_t)t * NB + cl * 16) * NH;
        ob[(size_t)(4 * kgrp + 0) * NH + jg] = hv0;
        ob[(size_t)(4 * kgrp + 1) * NH + jg] = hv1;
        ob[(size_t)(4 * kgrp + 2) * NH + jg] = hv2;
        ob[(size_t)(4 * kgrp + 3) * NH + jg] = hv3;
      }
      // shadow: acc(t+1) = bias + w_ih1 @ h0[t+1]
      if (t < SEQ - 1) {
        acc[0] = bias; acc[1] = bias; acc[2] = bias; acc[3] = bias;
#pragma unroll
        for (int kk = 0; kk < 16; ++kk)
          acc = MFMA16(as_f16x8(h0f[kk]), BFRAG(Wi, kk), acc);
      }
    }
  }
}

extern "C" void kernel_launch(void* const* d_in, const int* in_sizes, int n_in,
                              void* d_out, int out_size, void* d_ws, size_t ws_size,
                              hipStream_t stream) {
  (void)in_sizes; (void)n_in; (void)out_size; (void)ws_size;
  const float* x = (const float*)d_in[0];
  const float* hx = (const float*)d_in[1];
  const float* w_ih = (const float*)d_in[2];
  const float* w_hh = (const float*)d_in[3];
  const float* b_ih = (const float*)d_in[4];
  const float* b_hh = (const float*)d_in[5];
  float* out = (float*)d_out;
  char* ws = (char*)d_ws;

  // reset flags / progress / abort (first 1 KB of ws); rings are write-before-read
  hipMemsetAsync(d_ws, 0, 1024, stream);
  hipFuncSetAttribute((const void*)rnn_fused,
                      hipFuncAttributeMaxDynamicSharedMemorySize, LDS_BYTES);
  rnn_fused<<<dim3(64), dim3(256), LDS_BYTES, stream>>>(x, hx, w_ih, w_hh, b_ih,
                                                        b_hh, out, ws);
}